// Round 2
// baseline (64.858 us; speedup 1.0000x reference)
//
#include <hip/hip_runtime.h>

// MMDet RoI mask paste: masks [128,1,28,28] f32, boxes [128,4] f32 (xyxy),
// out [128,800,800] f32. Separable bilinear, align_corners=false, zeros pad.
//
// Write-BW-bound: 327.7 MB stores. R1 lesson: partial store waves (200/256
// lanes) cost exactly 22% -> make EVERY store a full 1024B wave store.
//
// One block = 16 image rows of one ROI. 128 threads x 25 iters, each iter
// the block writes 128 consecutive float4 (2 full wave stores of 1024B).
// ry[16][28] y-interpolated rows staged in LDS (<=2 rows per wave on read
// -> <=2-way bank aliasing = free).

#define RR 28
#define IMG 800
#define ROWS_PER_BLOCK 16
#define BLOCK 128
#define F4_PER_ROW (IMG / 4)                        // 200
#define F4_PER_BLOCK (ROWS_PER_BLOCK * F4_PER_ROW)  // 3200
#define ITERS (F4_PER_BLOCK / BLOCK)                // 25
#define GROUPS_PER_ROI (IMG / ROWS_PER_BLOCK)       // 50

__global__ __launch_bounds__(BLOCK) void roi_paste_kernel(
    const float* __restrict__ masks,   // [N,1,28,28]
    const float* __restrict__ boxes,   // [N,4]
    float* __restrict__ out) {         // [N,800,800]
  const int bid = blockIdx.x;
  const int n  = bid / GROUPS_PER_ROI;
  const int rg = bid % GROUPS_PER_ROI;
  const int rowbase = rg * ROWS_PER_BLOCK;

  const float bx0 = boxes[n * 4 + 0];
  const float by0 = boxes[n * 4 + 1];
  const float bx1 = boxes[n * 4 + 2];
  const float by1 = boxes[n * 4 + 3];
  const float sx = (float)RR / (bx1 - bx0);
  const float cx = (0.5f - bx0) * sx - 0.5f;
  const float sy = (float)RR / (by1 - by0);
  const float cy = (0.5f - by0) * sy - 0.5f;

  __shared__ float ry[ROWS_PER_BLOCK * RR];   // 16*28 floats = 1792 B

  // --- phase 1: y-interpolate 16 rows into LDS ---
  const float* mbase = masks + (size_t)n * (RR * RR);
  for (int e = threadIdx.x; e < ROWS_PER_BLOCK * RR; e += BLOCK) {
    const int r = e / RR;
    const int c = e - r * RR;
    const float py = fmaf((float)(rowbase + r), sy, cy);
    const float yf = floorf(py);
    const float wy = py - yf;
    const int yi = (int)yf;
    const bool va = (unsigned)yi < (unsigned)RR;
    const bool vb = (unsigned)(yi + 1) < (unsigned)RR;
    const int ya = min(max(yi, 0), RR - 1);
    const int yb = min(max(yi + 1, 0), RR - 1);
    const float a = va ? mbase[ya * RR + c] : 0.0f;
    const float b = vb ? mbase[yb * RR + c] : 0.0f;
    ry[e] = a * (1.0f - wy) + b * wy;
  }
  __syncthreads();

  // --- phase 2: x-interpolate + store, one float4 per thread per iter ---
  float* oblock = out + ((size_t)n * IMG + rowbase) * IMG;

#pragma unroll 1
  for (int j = 0; j < ITERS; ++j) {
    const unsigned i = (unsigned)(j * BLOCK) + threadIdx.x;  // [0, 3200)
    const unsigned row  = i / (unsigned)F4_PER_ROW;
    const unsigned col4 = i - row * (unsigned)F4_PER_ROW;
    const float* ryrow = ry + row * RR;
    const float xbf = (float)(col4 * 4u);
    float v[4];
#pragma unroll
    for (int k = 0; k < 4; ++k) {
      const float px = fmaf(xbf + (float)k, sx, cx);
      const float xf = floorf(px);
      const float wx = px - xf;
      const int xi = (int)xf;
      const bool va = (unsigned)xi < (unsigned)RR;
      const bool vb = (unsigned)(xi + 1) < (unsigned)RR;
      const int xa = min(max(xi, 0), RR - 1);
      const int xb = min(max(xi + 1, 0), RR - 1);
      const float a = ryrow[xa];
      const float b = ryrow[xb];
      const float wa = va ? (1.0f - wx) : 0.0f;
      const float wb = vb ? wx : 0.0f;
      v[k] = wa * a + wb * b;
    }
    *reinterpret_cast<float4*>(oblock + (size_t)row * IMG + col4 * 4u) =
        make_float4(v[0], v[1], v[2], v[3]);
  }
}

extern "C" void kernel_launch(void* const* d_in, const int* in_sizes, int n_in,
                              void* d_out, int out_size, void* d_ws, size_t ws_size,
                              hipStream_t stream) {
  const float* masks = (const float*)d_in[0];
  const float* boxes = (const float*)d_in[1];
  float* out = (float*)d_out;

  const int n_rois = in_sizes[1] / 4;                 // 128
  dim3 grid(n_rois * GROUPS_PER_ROI);                 // 6400 blocks
  dim3 block(BLOCK);
  roi_paste_kernel<<<grid, block, 0, stream>>>(masks, boxes, out);
}

// Round 4
// 64.704 us; speedup vs baseline: 1.0024x; 1.0024x over previous
//
#include <hip/hip_runtime.h>

// MMDet RoI mask paste: masks [128,1,28,28] f32, boxes [128,4] f32 (xyxy),
// out [128,800,800] f32. Separable bilinear, align_corners=false, zeros pad.
//
// Write-BW-bound: 327.7 MB stores, floor ~47.5us at fill-kernel BW (6.9TB/s).
// R1 (partial waves, 1 row/block): 61.8us. R2 (full waves, 16 rows/block):
// 64.9us -> store-lane efficiency is NOT the limiter. R3: A/B the L2
// write-allocate theory via nontemporal stores on the R1 structure.
// (nontemporal builtin needs a native ext_vector type, not HIP float4.)

#define RR 28        // mask resolution
#define IMG 800      // canvas H = W
#define PX_PER_THREAD 4
#define ROW_THREADS (IMG / PX_PER_THREAD)   // 200

typedef float vf4 __attribute__((ext_vector_type(4)));

__global__ __launch_bounds__(256) void roi_paste_kernel(
    const float* __restrict__ masks,   // [N,1,28,28]
    const float* __restrict__ boxes,   // [N,4] xyxy
    float* __restrict__ out) {         // [N,800,800]
  const int y = blockIdx.x;            // 0..799
  const int n = blockIdx.y;            // 0..127

  const float bx0 = boxes[n * 4 + 0];
  const float by0 = boxes[n * 4 + 1];
  const float bx1 = boxes[n * 4 + 2];
  const float by1 = boxes[n * 4 + 3];

  // --- per-row y interpolation into LDS (28 floats) ---
  __shared__ float ry[RR];
  const float py = ((float)y + 0.5f - by0) / (by1 - by0) * (float)RR - 0.5f;
  const float yfl = floorf(py);
  const float wy = py - yfl;
  const int yi = (int)yfl;

  const int t = threadIdx.x;
  if (t < RR) {
    const float* mrow = masks + (size_t)n * RR * RR;
    float a = (yi >= 0 && yi < RR)          ? mrow[yi * RR + t]       : 0.0f;
    float b = (yi + 1 >= 0 && yi + 1 < RR)  ? mrow[(yi + 1) * RR + t] : 0.0f;
    ry[t] = a * (1.0f - wy) + b * wy;
  }
  __syncthreads();

  if (t < ROW_THREADS) {
    const float xscale = (float)RR / (bx1 - bx0);
    const float xc = (0.5f - bx0) * xscale - 0.5f;
    const int xb = t * PX_PER_THREAD;
    vf4 pack;
#pragma unroll
    for (int k = 0; k < 4; ++k) {
      const float px = fmaf((float)(xb + k), xscale, xc);
      const float xfl = floorf(px);
      const float wx = px - xfl;
      const int xi = (int)xfl;
      const bool va = (unsigned)xi < (unsigned)RR;
      const bool vb = (unsigned)(xi + 1) < (unsigned)RR;
      const int xa = min(max(xi, 0), RR - 1);
      const int xb2 = min(max(xi + 1, 0), RR - 1);
      const float a = ry[xa];
      const float b = ry[xb2];
      const float wa = va ? (1.0f - wx) : 0.0f;
      const float wb = vb ? wx : 0.0f;
      pack[k] = wa * a + wb * b;
    }
    __builtin_nontemporal_store(
        pack, reinterpret_cast<vf4*>(
                  &out[((size_t)n * IMG + y) * IMG + xb]));
  }
}

extern "C" void kernel_launch(void* const* d_in, const int* in_sizes, int n_in,
                              void* d_out, int out_size, void* d_ws, size_t ws_size,
                              hipStream_t stream) {
  const float* masks = (const float*)d_in[0];
  const float* boxes = (const float*)d_in[1];
  float* out = (float*)d_out;

  const int n_rois = in_sizes[1] / 4;   // 128
  dim3 grid(IMG, n_rois);
  dim3 block(256);
  roi_paste_kernel<<<grid, block, 0, stream>>>(masks, boxes, out);
}